// Round 6
// baseline (170.039 us; speedup 1.0000x reference)
//
#include <hip/hip_runtime.h>
#include <hip/hip_bf16.h>
#include <math.h>

#define BB 32
#define NN 1024
#define DD 64
#define HH 128
#define KK 16
#define OD 8
#define M_TOT (BB*NN)

typedef unsigned long long u64;

// bucket = clamp((f32bits >> 21) - 400, 0, 254): exponent + 2 mantissa bits,
// strictly monotone in d2 (d2 >= 0). 255 reserved for self.
static __device__ __forceinline__ int d2b(float d2) {
  int v = (int)(__float_as_uint(d2) >> 21) - 400;
  v = v < 0 ? 0 : v;
  return v > 254 ? 254 : v;
}

// ---------------------------------------------------------------------------
// K1: Y = X @ W (64 rows x 128 cols / block, 512 thr, 4x4 acc/thread).
// EMIT_MASK: during X staging also compute mask = any(row != 0), emit
// maskf / pxy (inf-masked x,y) / degi = 0.
// ---------------------------------------------------------------------------
template <int CIN, bool EMIT_MASK>
__global__ __launch_bounds__(512) void k_gemm(const float* __restrict__ X,
                                              const float* __restrict__ W,
                                              float* __restrict__ Y,
                                              float* __restrict__ maskf,
                                              int* __restrict__ degi,
                                              float2* __restrict__ pxy) {
  __shared__ float Ws[32 * HH];      // 16 KB
  __shared__ float Xt[32 * 68];      // 8.5 KB, Xt[k][row]
  __shared__ int rowflag[64];
  __shared__ float2 praw[64];
  const int t = threadIdx.x;
  const size_t rowbase = (size_t)blockIdx.x * 64;

  if (EMIT_MASK && t < 64) rowflag[t] = 0;

  const int c4 = (t & 31) * 4;
  const int r4 = (t >> 5) * 4;

  float acc[4][4] = {{0.f}};

  for (int k0 = 0; k0 < CIN; k0 += 32) {
    __syncthreads();
    {
      const float4* Wt4 = (const float4*)(W + (size_t)k0 * HH);
      ((float4*)Ws)[t]       = Wt4[t];
      ((float4*)Ws)[t + 512] = Wt4[t + 512];
    }
    {
      const int row = t >> 3;        // 0..63
      const int kq  = t & 7;         // 0..7
      float4 v = *(const float4*)(X + (rowbase + row) * CIN + k0 + kq * 4);
      if (EMIT_MASK) {
        if (v.x != 0.f || v.y != 0.f || v.z != 0.f || v.w != 0.f)
          rowflag[row] = 1;          // benign race: all writers store 1
        if (k0 == 0 && kq == 0) praw[row] = make_float2(v.x, v.y);
      }
      Xt[(kq * 4 + 0) * 68 + row] = v.x;
      Xt[(kq * 4 + 1) * 68 + row] = v.y;
      Xt[(kq * 4 + 2) * 68 + row] = v.z;
      Xt[(kq * 4 + 3) * 68 + row] = v.w;
    }
    __syncthreads();
#pragma unroll
    for (int k = 0; k < 32; ++k) {
      const float4 xa = *(const float4*)&Xt[k * 68 + r4];
      const float4 wb = *(const float4*)&Ws[k * HH + c4];
      acc[0][0] += xa.x * wb.x; acc[0][1] += xa.x * wb.y; acc[0][2] += xa.x * wb.z; acc[0][3] += xa.x * wb.w;
      acc[1][0] += xa.y * wb.x; acc[1][1] += xa.y * wb.y; acc[1][2] += xa.y * wb.z; acc[1][3] += xa.y * wb.w;
      acc[2][0] += xa.z * wb.x; acc[2][1] += xa.z * wb.y; acc[2][2] += xa.z * wb.z; acc[2][3] += xa.z * wb.w;
      acc[3][0] += xa.w * wb.x; acc[3][1] += xa.w * wb.y; acc[3][2] += xa.w * wb.z; acc[3][3] += xa.w * wb.w;
    }
  }
#pragma unroll
  for (int i = 0; i < 4; ++i)
    *(float4*)(Y + (rowbase + r4 + i) * HH + c4) =
        make_float4(acc[i][0], acc[i][1], acc[i][2], acc[i][3]);

  if (EMIT_MASK && t < 64) {
    const size_t gr = rowbase + t;
    const int any = rowflag[t];
    maskf[gr] = any ? 1.f : 0.f;
    degi[gr] = 0;
    const float inf = __builtin_inff();
    pxy[gr] = any ? praw[t] : make_float2(inf, inf);
  }
}

// ---------------------------------------------------------------------------
// K2: exact 16-NN set per row, histogram selection with bucket-byte cache.
// 16 lanes/row, 16 rows/block. Pass 1: d2 once per candidate -> bucket byte
// cached in LDS + histogram atomic. Scan: cutoff bucket B*, ndef. Pass 2:
// SWAR-scan cached bytes; only hits (definites/contenders) do real work;
// contenders re-derive exact d2 for packed-key tie-exact extraction.
// ---------------------------------------------------------------------------
__global__ __launch_bounds__(256) void k_topk(const float2* __restrict__ pxy,
                                              const float* __restrict__ maskf,
                                              int* __restrict__ nbr,
                                              int* __restrict__ degi) {
  __shared__ float2 pls[NN];                 // 8 KB
  __shared__ unsigned hist[16][256];         // 16 KB
  __shared__ unsigned char bcache[16][NN];   // 16 KB
  __shared__ u64 lst[16][48];                // 6 KB
  __shared__ int dcnt[16];
  __shared__ int ccnt[16];

  const int b = blockIdx.x;
  const int t = threadIdx.x;
  const int rl = t >> 4;                // row within block, 0..15
  const int s  = t & 15;                // sublane within row, 0..15
  const int row = blockIdx.y * 16 + rl;
  const size_t r = (size_t)b * NN + row;

  {
    const float4* src = (const float4*)(pxy + (size_t)b * NN);
    float4* dst = (float4*)pls;
    dst[t] = src[t];
    dst[t + 256] = src[t + 256];
  }
  {
    const uint4 z4 = make_uint4(0u, 0u, 0u, 0u);
    uint4* h4 = (uint4*)hist[rl];
#pragma unroll
    for (int q = s; q < 64; q += 16) h4[q] = z4;
  }
  if (s == 0) { dcnt[rl] = 0; ccnt[rl] = 0; }
  __syncthreads();

  const bool valid = (maskf[r] != 0.f);
  const float2 pi = pls[row];
  const float xi = pi.x, yi = pi.y;
  unsigned* bcw = (unsigned*)&bcache[rl][0];

  // ---- pass 1: bucket every candidate once, cache byte, histogram ----
  if (valid) {
#pragma unroll 2
    for (int q = 0; q < 16; ++q) {
      const int j0 = q * 64 + s * 4;
      const float4 pa = *(const float4*)&pls[j0];
      const float4 pb = *(const float4*)&pls[j0 + 2];
      unsigned pk;
      {
        const float dx = __fsub_rn(xi, pa.x), dy = __fsub_rn(yi, pa.y);
        const float d2 = __fadd_rn(__fmul_rn(dx, dx), __fmul_rn(dy, dy));
        int bv = d2b(d2); if (j0 == row) bv = 255;
        pk = (unsigned)bv;
      }
      {
        const float dx = __fsub_rn(xi, pa.z), dy = __fsub_rn(yi, pa.w);
        const float d2 = __fadd_rn(__fmul_rn(dx, dx), __fmul_rn(dy, dy));
        int bv = d2b(d2); if (j0 + 1 == row) bv = 255;
        pk |= (unsigned)bv << 8;
      }
      {
        const float dx = __fsub_rn(xi, pb.x), dy = __fsub_rn(yi, pb.y);
        const float d2 = __fadd_rn(__fmul_rn(dx, dx), __fmul_rn(dy, dy));
        int bv = d2b(d2); if (j0 + 2 == row) bv = 255;
        pk |= (unsigned)bv << 16;
      }
      {
        const float dx = __fsub_rn(xi, pb.z), dy = __fsub_rn(yi, pb.w);
        const float d2 = __fadd_rn(__fmul_rn(dx, dx), __fmul_rn(dy, dy));
        int bv = d2b(d2); if (j0 + 3 == row) bv = 255;
        pk |= (unsigned)bv << 24;
      }
      bcw[q * 16 + s] = pk;
      atomicAdd(&hist[rl][pk & 255u], 1u);
      atomicAdd(&hist[rl][(pk >> 8) & 255u], 1u);
      atomicAdd(&hist[rl][(pk >> 16) & 255u], 1u);
      atomicAdd(&hist[rl][pk >> 24], 1u);
    }
  }
  __syncthreads();

  // ---- scan: find B*, ndef ----
  int ndef = 0, need = 0, cem = 0, Bstar = 255;
  if (valid) {
    unsigned seg = 0;
    const uint4* hp = (const uint4*)&hist[rl][s * 16];
#pragma unroll
    for (int i = 0; i < 4; ++i) {
      const uint4 h4 = hp[i];
      seg += h4.x + h4.y + h4.z + h4.w;
    }
    unsigned pre = seg;
#pragma unroll
    for (int off = 1; off < 16; off <<= 1) {
      const unsigned v = __shfl_up(pre, off, 16);
      if (s >= off) pre += v;
    }
    const unsigned preEx = pre - seg;
    int packed = -1;
    if (preEx < 16 && pre >= 16) {      // exactly one lane crosses
      unsigned cum = preEx;
      int Bs = 255, nd = 0;
      for (int i = 0; i < 16; ++i) {
        const unsigned h = hist[rl][s * 16 + i];
        if (cum + h >= 16) { Bs = s * 16 + i; nd = (int)cum; break; }
        cum += h;
      }
      packed = (Bs << 8) | nd;
    }
#pragma unroll
    for (int off = 1; off < 16; off <<= 1)
      packed = max(packed, __shfl_xor(packed, off, 16));
    Bstar = packed >> 8;
    ndef = packed & 255;
    need = 16 - ndef;

    // ---- pass 2: SWAR-scan cached bytes; hits only ----
    const unsigned thr1 = (unsigned)Bstar + 1u;   // byte <= Bstar  <=>  byte < thr1
    const bool fast = (thr1 <= 128u);
    const unsigned rep = thr1 * 0x01010101u;
    const uint4* bc4 = (const uint4*)&bcache[rl][0];
#pragma unroll 2
    for (int w4 = 0; w4 < 4; ++w4) {
      const uint4 xw = bc4[s * 4 + w4];
      unsigned wv[4] = {xw.x, xw.y, xw.z, xw.w};
#pragma unroll
      for (int wi = 0; wi < 4; ++wi) {
        const unsigned x = wv[wi];
        const bool anyhit = fast ? (((x - rep) & ~x & 0x80808080u) != 0u) : true;
        if (anyhit) {
          const int jb = s * 64 + w4 * 16 + wi * 4;
#pragma unroll
          for (int u = 0; u < 4; ++u) {
            const int bkt = (int)((x >> (8 * u)) & 255u);
            if (bkt < Bstar) {
              const int sl = atomicAdd(&dcnt[rl], 1);
              nbr[r * KK + sl] = jb + u;
              atomicAdd(&degi[b * NN + jb + u], 1);
            } else if (bkt == Bstar) {
              const int j = jb + u;
              const float2 p = pls[j];
              const float dx = __fsub_rn(xi, p.x), dy = __fsub_rn(yi, p.y);
              const float d2 = __fadd_rn(__fmul_rn(dx, dx), __fmul_rn(dy, dy));
              const int sl = atomicAdd(&ccnt[rl], 1);
              if (sl < 48) lst[rl][sl] = ((u64)__float_as_uint(d2) << 10) | (unsigned)j;
              ++cem;
            }
          }
        }
      }
    }
  }
  __syncthreads();

  // ---- contender extraction: iterated exact-min over packed keys ----
  int cn = cem;
#pragma unroll
  for (int off = 1; off < 16; off <<= 1) cn += __shfl_xor(cn, off, 16);
  cn = cn < 48 ? cn : 48;
  if (!valid) { cn = 0; need = 0; }

  u64 k0 = (s      < cn) ? lst[rl][s]      : ~0ull;
  u64 k1 = (s + 16 < cn) ? lst[rl][s + 16] : ~0ull;
  u64 k2 = (s + 32 < cn) ? lst[rl][s + 32] : ~0ull;

  int e = 0;
  while (__any(e < need)) {
    u64 m = k0 < k1 ? k0 : k1;
    m = m < k2 ? m : k2;
#pragma unroll
    for (int off = 1; off < 16; off <<= 1) {
      const u64 o = __shfl_xor(m, off, 16);
      m = o < m ? o : m;
    }
    if (e < need) {
      if (k0 == m) k0 = ~0ull;
      else if (k1 == m) k1 = ~0ull;
      else if (k2 == m) k2 = ~0ull;
      if (s == 0) {
        const int j = (int)(m & (u64)(NN - 1));
        nbr[r * KK + ndef + e] = j;
        atomicAdd(&degi[b * NN + j], 1);
      }
    }
    ++e;
  }
}

// ---------------------------------------------------------------------------
// K3: per-batch scan + dinv + reverse-edge fill (LDS cursors), one block
// per batch. cur[r] = global START of r's segment; rev[pos]=(src, s_src).
// ---------------------------------------------------------------------------
__global__ __launch_bounds__(1024) void k_graph(const int* __restrict__ degi,
                                                const float* __restrict__ maskf,
                                                const int* __restrict__ nbr,
                                                int* __restrict__ cur,
                                                float* __restrict__ dinv,
                                                int2* __restrict__ rev) {
  __shared__ int wsum[16];
  __shared__ int lcur[NN];
  const int b = blockIdx.x, t = threadIdx.x;
  const int lane = t & 63, w = t >> 6;
  const int r = b * NN + t;
  const int d = degi[r];
  int x = d;
#pragma unroll
  for (int off = 1; off < 64; off <<= 1) {
    int y = __shfl_up(x, off, 64);
    if (lane >= off) x += y;
  }
  if (lane == 63) wsum[w] = x;

  const float m = maskf[r];
  const float deg = (float)d + 2.f * m;
  const float dv = (deg > 0.f) ? (1.f / sqrtf(deg)) : 0.f;
  dinv[r] = dv;
  const float sv = dv * m;

  __syncthreads();
  if (w == 0) {
    int v = (lane < 16) ? wsum[lane] : 0;
#pragma unroll
    for (int off = 1; off < 16; off <<= 1) {
      int y = __shfl_up(v, off, 64);
      if (lane >= off) v += y;
    }
    if (lane < 16) wsum[lane] = v;
  }
  __syncthreads();
  const int start = b * (NN * KK) + (w ? wsum[w - 1] : 0) + x - d;  // exclusive
  lcur[t] = start;
  cur[r] = start;
  __syncthreads();

  if (m != 0.f) {
    const int sb = __float_as_int(sv);
    const int4* n4 = (const int4*)(nbr + (size_t)r * KK);
#pragma unroll
    for (int q = 0; q < 4; ++q) {
      int4 v = n4[q];
      int nb[4] = {v.x, v.y, v.z, v.w};
#pragma unroll
      for (int u = 0; u < 4; ++u) {
        const int pos = atomicAdd(&lcur[nb[u]], 1);
        rev[pos] = make_int2(r, sb);
      }
    }
  }
}

// ---------------------------------------------------------------------------
// K4: GCN via reverse-CSR gather. 32 lanes per node, each owns 4 channels.
// FUSE_OUT folds in out = (h @ W_out + b_out) * maskf.
// ---------------------------------------------------------------------------
template <bool FUSE_OUT>
__global__ __launch_bounds__(256) void k_gcn(const float* __restrict__ y,
                                             const float* __restrict__ dinv,
                                             const int* __restrict__ degi,
                                             const int* __restrict__ cur,
                                             const int2* __restrict__ rev,
                                             const float* __restrict__ bias,
                                             float* __restrict__ hout,
                                             const float* __restrict__ Wo,
                                             const float* __restrict__ bo,
                                             const float* __restrict__ maskf,
                                             float* __restrict__ out) {
  const int t = threadIdx.x;
  const int r = blockIdx.x * 8 + (t >> 5);
  const int lane = t & 31;
  const int cnt = degi[r];
  const int off = cur[r];
  const float di = dinv[r];

  float4 acc = make_float4(0.f, 0.f, 0.f, 0.f);
  int e = 0;
  for (; e + 2 <= cnt; e += 2) {
    const int2 e0 = rev[off + e];
    const int2 e1 = rev[off + e + 1];
    const float4 y0 = *(const float4*)(y + (size_t)e0.x * HH + lane * 4);
    const float4 y1 = *(const float4*)(y + (size_t)e1.x * HH + lane * 4);
    const float s0 = __int_as_float(e0.y);
    const float s1 = __int_as_float(e1.y);
    acc.x += s0 * y0.x; acc.y += s0 * y0.y; acc.z += s0 * y0.z; acc.w += s0 * y0.w;
    acc.x += s1 * y1.x; acc.y += s1 * y1.y; acc.z += s1 * y1.z; acc.w += s1 * y1.w;
  }
  if (e < cnt) {
    const int2 e0 = rev[off + e];
    const float4 y0 = *(const float4*)(y + (size_t)e0.x * HH + lane * 4);
    const float s0 = __int_as_float(e0.y);
    acc.x += s0 * y0.x; acc.y += s0 * y0.y; acc.z += s0 * y0.z; acc.w += s0 * y0.w;
  }

  const float4 ys = *(const float4*)(y + (size_t)r * HH + lane * 4);
  const float4 bb = *(const float4*)(bias + lane * 4);
  const float t2 = 2.f * di * di;
  float4 h;
  h.x = tanhf(di * acc.x + t2 * ys.x + bb.x);
  h.y = tanhf(di * acc.y + t2 * ys.y + bb.y);
  h.z = tanhf(di * acc.z + t2 * ys.z + bb.z);
  h.w = tanhf(di * acc.w + t2 * ys.w + bb.w);

  if (!FUSE_OUT) {
    *(float4*)(hout + (size_t)r * HH + lane * 4) = h;
  } else {
    const float4* W4 = (const float4*)(Wo + (size_t)lane * 4 * OD);
    float o8[OD];
#pragma unroll
    for (int o = 0; o < OD; ++o) o8[o] = 0.f;
#pragma unroll
    for (int cc = 0; cc < 4; ++cc) {
      const float hc = (cc == 0) ? h.x : (cc == 1) ? h.y : (cc == 2) ? h.z : h.w;
      const float4 wa = W4[cc * 2];
      const float4 wbq = W4[cc * 2 + 1];
      o8[0] += hc * wa.x;  o8[1] += hc * wa.y;  o8[2] += hc * wa.z;  o8[3] += hc * wa.w;
      o8[4] += hc * wbq.x; o8[5] += hc * wbq.y; o8[6] += hc * wbq.z; o8[7] += hc * wbq.w;
    }
#pragma unroll
    for (int offx = 1; offx < 32; offx <<= 1) {
#pragma unroll
      for (int o = 0; o < OD; ++o) o8[o] += __shfl_xor(o8[o], offx, 32);
    }
    if (lane == 0) {
      const float mf = maskf[r];
      const float4 b0 = *(const float4*)(bo);
      const float4 b1 = *(const float4*)(bo + 4);
      float4* orow = (float4*)(out + (size_t)r * OD);
      orow[0] = make_float4((o8[0] + b0.x) * mf, (o8[1] + b0.y) * mf,
                            (o8[2] + b0.z) * mf, (o8[3] + b0.w) * mf);
      orow[1] = make_float4((o8[4] + b1.x) * mf, (o8[5] + b1.y) * mf,
                            (o8[6] + b1.z) * mf, (o8[7] + b1.w) * mf);
    }
  }
}

// ---------------------------------------------------------------------------
extern "C" void kernel_launch(void* const* d_in, const int* in_sizes, int n_in,
                              void* d_out, int out_size, void* d_ws, size_t ws_size,
                              hipStream_t stream) {
  (void)in_sizes; (void)n_in; (void)out_size; (void)ws_size;
  const float* obs = (const float*)d_in[0];
  const float* W1  = (const float*)d_in[1];
  const float* b1  = (const float*)d_in[2];
  const float* W2  = (const float*)d_in[3];
  const float* b2  = (const float*)d_in[4];
  const float* Wo  = (const float*)d_in[5];
  const float* bo  = (const float*)d_in[6];
  float* out = (float*)d_out;

  char* ws = (char*)d_ws;
  float* maskf = (float*)(ws);                             // 128 KB
  int*   degi  = (int*)  (ws + (size_t)(128 << 10));       // 128 KB
  float* dinv  = (float*)(ws + (size_t)(256 << 10));       // 128 KB
  int*   cur   = (int*)  (ws + (size_t)(384 << 10));       // 128 KB
  float2* pxy  = (float2*)(ws + (size_t)(512 << 10));      // 256 KB
  int*   nbr   = (int*)  (ws + (size_t)(1u << 20));        // 2 MB
  int2*  rev   = (int2*) (ws + (size_t)(3u << 20));        // 4 MB
  float* ybuf  = (float*)(ws + (size_t)(7u << 20));        // 16 MB
  float* hbuf  = (float*)(ws + (size_t)(23u << 20));       // 16 MB

  k_gemm<DD, true><<<M_TOT / 64, 512, 0, stream>>>(obs, W1, ybuf, maskf, degi, pxy);
  k_topk<<<dim3(BB, NN / 16), 256, 0, stream>>>(pxy, maskf, nbr, degi);
  k_graph<<<BB, 1024, 0, stream>>>(degi, maskf, nbr, cur, dinv, rev);
  k_gcn<false><<<M_TOT / 8, 256, 0, stream>>>(ybuf, dinv, degi, cur, rev, b1, hbuf,
                                              nullptr, nullptr, nullptr, nullptr);
  k_gemm<HH, false><<<M_TOT / 64, 512, 0, stream>>>(hbuf, W2, ybuf, nullptr, nullptr, nullptr);
  k_gcn<true><<<M_TOT / 8, 256, 0, stream>>>(ybuf, dinv, degi, cur, rev, b2, nullptr,
                                             Wo, bo, maskf, out);
}

// Round 7
// 155.613 us; speedup vs baseline: 1.0927x; 1.0927x over previous
//
#include <hip/hip_runtime.h>
#include <hip/hip_bf16.h>
#include <math.h>

#define BB 32
#define NN 1024
#define DD 64
#define HH 128
#define KK 16
#define OD 8
#define M_TOT (BB*NN)

typedef unsigned long long u64;

// 7-bit bucket: clamp((f32bits >> 22) - 200, 0, 126); self uses 127.
// Strictly monotone in d2 (d2 >= 0, exponent+1 mantissa bit). All bucket
// bytes <= 127 -> SWAR compares below are borrow-free and exact.
static __device__ __forceinline__ int d2b7(float d2) {
  int v = (int)(__float_as_uint(d2) >> 22) - 200;
  v = v < 0 ? 0 : v;
  return v > 126 ? 126 : v;
}

// ---------------------------------------------------------------------------
// K1: Y = X @ W (64 rows x 128 cols / block, 512 thr, 4x4 acc/thread).
// EMIT_MASK: during X staging also compute mask = any(row != 0), emit
// maskf / pxy (inf-masked x,y) / degi = 0.
// ---------------------------------------------------------------------------
template <int CIN, bool EMIT_MASK>
__global__ __launch_bounds__(512) void k_gemm(const float* __restrict__ X,
                                              const float* __restrict__ W,
                                              float* __restrict__ Y,
                                              float* __restrict__ maskf,
                                              int* __restrict__ degi,
                                              float2* __restrict__ pxy) {
  __shared__ float Ws[32 * HH];      // 16 KB
  __shared__ float Xt[32 * 68];      // 8.5 KB, Xt[k][row]
  __shared__ int rowflag[64];
  __shared__ float2 praw[64];
  const int t = threadIdx.x;
  const size_t rowbase = (size_t)blockIdx.x * 64;

  if (EMIT_MASK && t < 64) rowflag[t] = 0;

  const int c4 = (t & 31) * 4;
  const int r4 = (t >> 5) * 4;

  float acc[4][4] = {{0.f}};

  for (int k0 = 0; k0 < CIN; k0 += 32) {
    __syncthreads();
    {
      const float4* Wt4 = (const float4*)(W + (size_t)k0 * HH);
      ((float4*)Ws)[t]       = Wt4[t];
      ((float4*)Ws)[t + 512] = Wt4[t + 512];
    }
    {
      const int row = t >> 3;        // 0..63
      const int kq  = t & 7;         // 0..7
      float4 v = *(const float4*)(X + (rowbase + row) * CIN + k0 + kq * 4);
      if (EMIT_MASK) {
        if (v.x != 0.f || v.y != 0.f || v.z != 0.f || v.w != 0.f)
          rowflag[row] = 1;          // benign race: all writers store 1
        if (k0 == 0 && kq == 0) praw[row] = make_float2(v.x, v.y);
      }
      Xt[(kq * 4 + 0) * 68 + row] = v.x;
      Xt[(kq * 4 + 1) * 68 + row] = v.y;
      Xt[(kq * 4 + 2) * 68 + row] = v.z;
      Xt[(kq * 4 + 3) * 68 + row] = v.w;
    }
    __syncthreads();
#pragma unroll
    for (int k = 0; k < 32; ++k) {
      const float4 xa = *(const float4*)&Xt[k * 68 + r4];
      const float4 wb = *(const float4*)&Ws[k * HH + c4];
      acc[0][0] += xa.x * wb.x; acc[0][1] += xa.x * wb.y; acc[0][2] += xa.x * wb.z; acc[0][3] += xa.x * wb.w;
      acc[1][0] += xa.y * wb.x; acc[1][1] += xa.y * wb.y; acc[1][2] += xa.y * wb.z; acc[1][3] += xa.y * wb.w;
      acc[2][0] += xa.z * wb.x; acc[2][1] += xa.z * wb.y; acc[2][2] += xa.z * wb.z; acc[2][3] += xa.z * wb.w;
      acc[3][0] += xa.w * wb.x; acc[3][1] += xa.w * wb.y; acc[3][2] += xa.w * wb.z; acc[3][3] += xa.w * wb.w;
    }
  }
#pragma unroll
  for (int i = 0; i < 4; ++i)
    *(float4*)(Y + (rowbase + r4 + i) * HH + c4) =
        make_float4(acc[i][0], acc[i][1], acc[i][2], acc[i][3]);

  if (EMIT_MASK && t < 64) {
    const size_t gr = rowbase + t;
    const int any = rowflag[t];
    maskf[gr] = any ? 1.f : 0.f;
    degi[gr] = 0;
    const float inf = __builtin_inff();
    pxy[gr] = any ? praw[t] : make_float2(inf, inf);
  }
}

// ---------------------------------------------------------------------------
// K2: exact 16-NN set per row. 16 lanes/row, 16 rows/block.
// Lane s owns candidates [s*64, s*64+64), staggered reads ((i+s)&63 rotation
// -> conflict-free LDS). Bucket bytes (7-bit) kept in 16 VGPRs. Cutoff via
// branch-free binary search on cnt(<=X): SWAR popcount over the 16 cached
// words + shfl reduce across the 16-lane group. No LDS histogram, no LDS
// byte cache, no histogram atomics. Pass 2 SWAR-classifies the registers:
// bucket < B* -> definite; == B* -> contender with exact packed key
// (d2 bits<<10 | idx, so JAX's lowest-index-on-tie is preserved exactly).
// ---------------------------------------------------------------------------
__global__ __launch_bounds__(256) void k_topk(const float2* __restrict__ pxy,
                                              const float* __restrict__ maskf,
                                              int* __restrict__ nbr,
                                              int* __restrict__ degi) {
  __shared__ float2 pls[NN];            // 8 KB
  __shared__ u64 lst[16][64];           // 8 KB contender lists
  __shared__ int dcnt[16];
  __shared__ int ccnt[16];

  const int b = blockIdx.x;
  const int t = threadIdx.x;
  const int rl = t >> 4;                // row within block, 0..15
  const int s  = t & 15;                // sublane within row, 0..15
  const int row = blockIdx.y * 16 + rl;
  const size_t r = (size_t)b * NN + row;

  {
    const float4* src = (const float4*)(pxy + (size_t)b * NN);
    float4* dst = (float4*)pls;
    dst[t] = src[t];
    dst[t + 256] = src[t + 256];
  }
  if (s == 0) { dcnt[rl] = 0; ccnt[rl] = 0; }
  __syncthreads();

  const bool valid = (maskf[r] != 0.f);
  const float2 pi = pls[row];
  const float xi = pi.x, yi = pi.y;

  // ---- pass 1: bucket 64 own candidates into 16 packed register words ----
  unsigned cache[16];
  if (valid) {
#pragma unroll
    for (int q = 0; q < 16; ++q) {
      unsigned pk = 0;
#pragma unroll
      for (int u = 0; u < 4; ++u) {
        const int i = q * 4 + u;
        const int j = s * 64 + ((i + s) & 63);
        const float2 p = pls[j];
        const float dx = __fsub_rn(xi, p.x);
        const float dy = __fsub_rn(yi, p.y);
        const float d2 = __fadd_rn(__fmul_rn(dx, dx), __fmul_rn(dy, dy));
        int bv = d2b7(d2);
        if (j == row) bv = 127;                    // self: above any cutoff
        pk |= (unsigned)bv << (8 * u);
      }
      cache[q] = pk;
    }
  } else {
#pragma unroll
    for (int q = 0; q < 16; ++q) cache[q] = 0x7F7F7F7Fu;
  }

  // ---- binary search for B* = min X with cnt(<=X) >= 16; ndef = cnt(<B*) ----
  int lo = 0, hi = 126, ndef = 0;
#pragma unroll
  for (int it = 0; it < 7; ++it) {
    const int mid = (lo + hi) >> 1;
    // cnt(<= mid): bytes < mid+1; K = (127 + mid+1) per byte; borrow-free.
    const unsigned K = (unsigned)(128 + mid) * 0x01010101u;
    int c = 0;
#pragma unroll
    for (int q = 0; q < 16; ++q)
      c += __popc((K - cache[q]) & 0x80808080u);
#pragma unroll
    for (int off = 1; off < 16; off <<= 1)
      c += __shfl_xor(c, off, 16);
    const bool ge = (c >= 16);
    if (ge) hi = mid;
    else { lo = mid + 1; ndef = c; }
  }
  const int Bstar = lo;
  int need = 16 - ndef;

  // ---- pass 2: SWAR classify cached bytes; only hits do real work ----
  int cem = 0;
  if (valid) {
    const unsigned Klo = (unsigned)(127 + Bstar) * 0x01010101u;  // bytes < B*
    const unsigned Khi = Klo + 0x01010101u;                      // bytes <= B*
#pragma unroll
    for (int q = 0; q < 16; ++q) {
      const unsigned w = cache[q];
      const unsigned mLE = (Khi - w) & 0x80808080u;
      if (mLE) {
        const unsigned mLT = (Klo - w) & 0x80808080u;
#pragma unroll
        for (int u = 0; u < 4; ++u) {
          const unsigned bit = 0x80u << (8 * u);
          if (mLE & bit) {
            const int j = s * 64 + ((q * 4 + u + s) & 63);
            if (mLT & bit) {               // definite top-16 member
              const int sl = atomicAdd(&dcnt[rl], 1);
              nbr[r * KK + sl] = j;
              atomicAdd(&degi[b * NN + j], 1);
            } else {                        // contender (bucket == B*)
              const float2 p = pls[j];
              const float dx = __fsub_rn(xi, p.x);
              const float dy = __fsub_rn(yi, p.y);
              const float d2 = __fadd_rn(__fmul_rn(dx, dx), __fmul_rn(dy, dy));
              const int sl = atomicAdd(&ccnt[rl], 1);
              if (sl < 64) lst[rl][sl] = ((u64)__float_as_uint(d2) << 10) | (unsigned)j;
              ++cem;
            }
          }
        }
      }
    }
  }
  __syncthreads();

  // ---- contender extraction: iterated exact-min over packed keys ----
  int cn = cem;
#pragma unroll
  for (int off = 1; off < 16; off <<= 1) cn += __shfl_xor(cn, off, 16);
  cn = cn < 64 ? cn : 64;
  if (!valid) { cn = 0; need = 0; }

  u64 k0 = (s      < cn) ? lst[rl][s]      : ~0ull;
  u64 k1 = (s + 16 < cn) ? lst[rl][s + 16] : ~0ull;
  u64 k2 = (s + 32 < cn) ? lst[rl][s + 32] : ~0ull;
  u64 k3 = (s + 48 < cn) ? lst[rl][s + 48] : ~0ull;

  int e = 0;
  while (__any(e < need)) {
    u64 m01 = k0 < k1 ? k0 : k1;
    u64 m23 = k2 < k3 ? k2 : k3;
    u64 m = m01 < m23 ? m01 : m23;
#pragma unroll
    for (int off = 1; off < 16; off <<= 1) {
      const u64 o = __shfl_xor(m, off, 16);
      m = o < m ? o : m;
    }
    if (e < need) {
      if (k0 == m) k0 = ~0ull;
      else if (k1 == m) k1 = ~0ull;
      else if (k2 == m) k2 = ~0ull;
      else if (k3 == m) k3 = ~0ull;
      if (s == 0) {
        const int j = (int)(m & (u64)(NN - 1));
        nbr[r * KK + ndef + e] = j;
        atomicAdd(&degi[b * NN + j], 1);
      }
    }
    ++e;
  }
}

// ---------------------------------------------------------------------------
// K3: per-batch scan + dinv + reverse-edge fill (LDS cursors), one block
// per batch. cur[r] = global START of r's segment; rev[pos]=(src, s_src).
// ---------------------------------------------------------------------------
__global__ __launch_bounds__(1024) void k_graph(const int* __restrict__ degi,
                                                const float* __restrict__ maskf,
                                                const int* __restrict__ nbr,
                                                int* __restrict__ cur,
                                                float* __restrict__ dinv,
                                                int2* __restrict__ rev) {
  __shared__ int wsum[16];
  __shared__ int lcur[NN];
  const int b = blockIdx.x, t = threadIdx.x;
  const int lane = t & 63, w = t >> 6;
  const int r = b * NN + t;
  const int d = degi[r];
  int x = d;
#pragma unroll
  for (int off = 1; off < 64; off <<= 1) {
    int y = __shfl_up(x, off, 64);
    if (lane >= off) x += y;
  }
  if (lane == 63) wsum[w] = x;

  const float m = maskf[r];
  const float deg = (float)d + 2.f * m;
  const float dv = (deg > 0.f) ? (1.f / sqrtf(deg)) : 0.f;
  dinv[r] = dv;
  const float sv = dv * m;

  __syncthreads();
  if (w == 0) {
    int v = (lane < 16) ? wsum[lane] : 0;
#pragma unroll
    for (int off = 1; off < 16; off <<= 1) {
      int y = __shfl_up(v, off, 64);
      if (lane >= off) v += y;
    }
    if (lane < 16) wsum[lane] = v;
  }
  __syncthreads();
  const int start = b * (NN * KK) + (w ? wsum[w - 1] : 0) + x - d;  // exclusive
  lcur[t] = start;
  cur[r] = start;
  __syncthreads();

  if (m != 0.f) {
    const int sb = __float_as_int(sv);
    const int4* n4 = (const int4*)(nbr + (size_t)r * KK);
#pragma unroll
    for (int q = 0; q < 4; ++q) {
      int4 v = n4[q];
      int nb[4] = {v.x, v.y, v.z, v.w};
#pragma unroll
      for (int u = 0; u < 4; ++u) {
        const int pos = atomicAdd(&lcur[nb[u]], 1);
        rev[pos] = make_int2(r, sb);
      }
    }
  }
}

// ---------------------------------------------------------------------------
// K4: GCN via reverse-CSR gather. 32 lanes per node, each owns 4 channels.
// FUSE_OUT folds in out = (h @ W_out + b_out) * maskf.
// ---------------------------------------------------------------------------
template <bool FUSE_OUT>
__global__ __launch_bounds__(256) void k_gcn(const float* __restrict__ y,
                                             const float* __restrict__ dinv,
                                             const int* __restrict__ degi,
                                             const int* __restrict__ cur,
                                             const int2* __restrict__ rev,
                                             const float* __restrict__ bias,
                                             float* __restrict__ hout,
                                             const float* __restrict__ Wo,
                                             const float* __restrict__ bo,
                                             const float* __restrict__ maskf,
                                             float* __restrict__ out) {
  const int t = threadIdx.x;
  const int r = blockIdx.x * 8 + (t >> 5);
  const int lane = t & 31;
  const int cnt = degi[r];
  const int off = cur[r];
  const float di = dinv[r];

  float4 acc = make_float4(0.f, 0.f, 0.f, 0.f);
  int e = 0;
  for (; e + 2 <= cnt; e += 2) {
    const int2 e0 = rev[off + e];
    const int2 e1 = rev[off + e + 1];
    const float4 y0 = *(const float4*)(y + (size_t)e0.x * HH + lane * 4);
    const float4 y1 = *(const float4*)(y + (size_t)e1.x * HH + lane * 4);
    const float s0 = __int_as_float(e0.y);
    const float s1 = __int_as_float(e1.y);
    acc.x += s0 * y0.x; acc.y += s0 * y0.y; acc.z += s0 * y0.z; acc.w += s0 * y0.w;
    acc.x += s1 * y1.x; acc.y += s1 * y1.y; acc.z += s1 * y1.z; acc.w += s1 * y1.w;
  }
  if (e < cnt) {
    const int2 e0 = rev[off + e];
    const float4 y0 = *(const float4*)(y + (size_t)e0.x * HH + lane * 4);
    const float s0 = __int_as_float(e0.y);
    acc.x += s0 * y0.x; acc.y += s0 * y0.y; acc.z += s0 * y0.z; acc.w += s0 * y0.w;
  }

  const float4 ys = *(const float4*)(y + (size_t)r * HH + lane * 4);
  const float4 bb = *(const float4*)(bias + lane * 4);
  const float t2 = 2.f * di * di;
  float4 h;
  h.x = tanhf(di * acc.x + t2 * ys.x + bb.x);
  h.y = tanhf(di * acc.y + t2 * ys.y + bb.y);
  h.z = tanhf(di * acc.z + t2 * ys.z + bb.z);
  h.w = tanhf(di * acc.w + t2 * ys.w + bb.w);

  if (!FUSE_OUT) {
    *(float4*)(hout + (size_t)r * HH + lane * 4) = h;
  } else {
    const float4* W4 = (const float4*)(Wo + (size_t)lane * 4 * OD);
    float o8[OD];
#pragma unroll
    for (int o = 0; o < OD; ++o) o8[o] = 0.f;
#pragma unroll
    for (int cc = 0; cc < 4; ++cc) {
      const float hc = (cc == 0) ? h.x : (cc == 1) ? h.y : (cc == 2) ? h.z : h.w;
      const float4 wa = W4[cc * 2];
      const float4 wbq = W4[cc * 2 + 1];
      o8[0] += hc * wa.x;  o8[1] += hc * wa.y;  o8[2] += hc * wa.z;  o8[3] += hc * wa.w;
      o8[4] += hc * wbq.x; o8[5] += hc * wbq.y; o8[6] += hc * wbq.z; o8[7] += hc * wbq.w;
    }
#pragma unroll
    for (int offx = 1; offx < 32; offx <<= 1) {
#pragma unroll
      for (int o = 0; o < OD; ++o) o8[o] += __shfl_xor(o8[o], offx, 32);
    }
    if (lane == 0) {
      const float mf = maskf[r];
      const float4 b0 = *(const float4*)(bo);
      const float4 b1 = *(const float4*)(bo + 4);
      float4* orow = (float4*)(out + (size_t)r * OD);
      orow[0] = make_float4((o8[0] + b0.x) * mf, (o8[1] + b0.y) * mf,
                            (o8[2] + b0.z) * mf, (o8[3] + b0.w) * mf);
      orow[1] = make_float4((o8[4] + b1.x) * mf, (o8[5] + b1.y) * mf,
                            (o8[6] + b1.z) * mf, (o8[7] + b1.w) * mf);
    }
  }
}

// ---------------------------------------------------------------------------
extern "C" void kernel_launch(void* const* d_in, const int* in_sizes, int n_in,
                              void* d_out, int out_size, void* d_ws, size_t ws_size,
                              hipStream_t stream) {
  (void)in_sizes; (void)n_in; (void)out_size; (void)ws_size;
  const float* obs = (const float*)d_in[0];
  const float* W1  = (const float*)d_in[1];
  const float* b1  = (const float*)d_in[2];
  const float* W2  = (const float*)d_in[3];
  const float* b2  = (const float*)d_in[4];
  const float* Wo  = (const float*)d_in[5];
  const float* bo  = (const float*)d_in[6];
  float* out = (float*)d_out;

  char* ws = (char*)d_ws;
  float* maskf = (float*)(ws);                             // 128 KB
  int*   degi  = (int*)  (ws + (size_t)(128 << 10));       // 128 KB
  float* dinv  = (float*)(ws + (size_t)(256 << 10));       // 128 KB
  int*   cur   = (int*)  (ws + (size_t)(384 << 10));       // 128 KB
  float2* pxy  = (float2*)(ws + (size_t)(512 << 10));      // 256 KB
  int*   nbr   = (int*)  (ws + (size_t)(1u << 20));        // 2 MB
  int2*  rev   = (int2*) (ws + (size_t)(3u << 20));        // 4 MB
  float* ybuf  = (float*)(ws + (size_t)(7u << 20));        // 16 MB
  float* hbuf  = (float*)(ws + (size_t)(23u << 20));       // 16 MB

  k_gemm<DD, true><<<M_TOT / 64, 512, 0, stream>>>(obs, W1, ybuf, maskf, degi, pxy);
  k_topk<<<dim3(BB, NN / 16), 256, 0, stream>>>(pxy, maskf, nbr, degi);
  k_graph<<<BB, 1024, 0, stream>>>(degi, maskf, nbr, cur, dinv, rev);
  k_gcn<false><<<M_TOT / 8, 256, 0, stream>>>(ybuf, dinv, degi, cur, rev, b1, hbuf,
                                              nullptr, nullptr, nullptr, nullptr);
  k_gemm<HH, false><<<M_TOT / 64, 512, 0, stream>>>(hbuf, W2, ybuf, nullptr, nullptr, nullptr);
  k_gcn<true><<<M_TOT / 8, 256, 0, stream>>>(ybuf, dinv, degi, cur, rev, b2, nullptr,
                                             Wo, bo, maskf, out);
}

// Round 8
// 138.312 us; speedup vs baseline: 1.2294x; 1.1251x over previous
//
#include <hip/hip_runtime.h>
#include <hip/hip_bf16.h>
#include <math.h>

#define BB 32
#define NN 1024
#define DD 64
#define HH 128
#define KK 16
#define OD 8
#define M_TOT (BB*NN)

typedef unsigned long long u64;

// 7-bit bucket: clamp((f32bits >> 22) - 200, 0, 126); self uses 127.
// Strictly monotone in d2 (d2 >= 0). All bucket bytes <= 127 -> the SWAR
// subtracts below are borrow-free per byte (K bytes >= 128) and exact in u64.
static __device__ __forceinline__ int d2b7(float d2) {
  int v = (int)(__float_as_uint(d2) >> 22) - 200;
  v = v < 0 ? 0 : v;
  return v > 126 ? 126 : v;
}

// ---------------------------------------------------------------------------
// K1: Y = X @ W (64 rows x 128 cols / block, 512 thr, 4x4 acc/thread).
// EMIT_MASK: during X staging also compute mask = any(row != 0), emit
// maskf / pxy (inf-masked x,y) / degi = 0.
// ---------------------------------------------------------------------------
template <int CIN, bool EMIT_MASK>
__global__ __launch_bounds__(512) void k_gemm(const float* __restrict__ X,
                                              const float* __restrict__ W,
                                              float* __restrict__ Y,
                                              float* __restrict__ maskf,
                                              int* __restrict__ degi,
                                              float2* __restrict__ pxy) {
  __shared__ float Ws[32 * HH];      // 16 KB
  __shared__ float Xt[32 * 68];      // 8.5 KB, Xt[k][row]
  __shared__ int rowflag[64];
  __shared__ float2 praw[64];
  const int t = threadIdx.x;
  const size_t rowbase = (size_t)blockIdx.x * 64;

  if (EMIT_MASK && t < 64) rowflag[t] = 0;

  const int c4 = (t & 31) * 4;
  const int r4 = (t >> 5) * 4;

  float acc[4][4] = {{0.f}};

  for (int k0 = 0; k0 < CIN; k0 += 32) {
    __syncthreads();
    {
      const float4* Wt4 = (const float4*)(W + (size_t)k0 * HH);
      ((float4*)Ws)[t]       = Wt4[t];
      ((float4*)Ws)[t + 512] = Wt4[t + 512];
    }
    {
      const int row = t >> 3;        // 0..63
      const int kq  = t & 7;         // 0..7
      float4 v = *(const float4*)(X + (rowbase + row) * CIN + k0 + kq * 4);
      if (EMIT_MASK) {
        if (v.x != 0.f || v.y != 0.f || v.z != 0.f || v.w != 0.f)
          rowflag[row] = 1;          // benign race: all writers store 1
        if (k0 == 0 && kq == 0) praw[row] = make_float2(v.x, v.y);
      }
      Xt[(kq * 4 + 0) * 68 + row] = v.x;
      Xt[(kq * 4 + 1) * 68 + row] = v.y;
      Xt[(kq * 4 + 2) * 68 + row] = v.z;
      Xt[(kq * 4 + 3) * 68 + row] = v.w;
    }
    __syncthreads();
#pragma unroll
    for (int k = 0; k < 32; ++k) {
      const float4 xa = *(const float4*)&Xt[k * 68 + r4];
      const float4 wb = *(const float4*)&Ws[k * HH + c4];
      acc[0][0] += xa.x * wb.x; acc[0][1] += xa.x * wb.y; acc[0][2] += xa.x * wb.z; acc[0][3] += xa.x * wb.w;
      acc[1][0] += xa.y * wb.x; acc[1][1] += xa.y * wb.y; acc[1][2] += xa.y * wb.z; acc[1][3] += xa.y * wb.w;
      acc[2][0] += xa.z * wb.x; acc[2][1] += xa.z * wb.y; acc[2][2] += xa.z * wb.z; acc[2][3] += xa.z * wb.w;
      acc[3][0] += xa.w * wb.x; acc[3][1] += xa.w * wb.y; acc[3][2] += xa.w * wb.z; acc[3][3] += xa.w * wb.w;
    }
  }
#pragma unroll
  for (int i = 0; i < 4; ++i)
    *(float4*)(Y + (rowbase + r4 + i) * HH + c4) =
        make_float4(acc[i][0], acc[i][1], acc[i][2], acc[i][3]);

  if (EMIT_MASK && t < 64) {
    const size_t gr = rowbase + t;
    const int any = rowflag[t];
    maskf[gr] = any ? 1.f : 0.f;
    degi[gr] = 0;
    const float inf = __builtin_inff();
    pxy[gr] = any ? praw[t] : make_float2(inf, inf);
  }
}

// ---------------------------------------------------------------------------
// K2: exact 16-NN set per row. 16 lanes/row, 16 rows/block. Lane s owns
// candidates [s*64, s*64+64), staggered ((i+s)&63) conflict-free LDS reads.
// Bucket bytes packed into 8 u64 VGPRs. Cutoff B* via 7-probe binary search
// with u64-SWAR popcount (borrow-free). Pass 2 SWAR-classifies registers;
// contenders (== B*) carry exact packed keys (d2 bits << 10 | idx) so JAX's
// lowest-index-on-tie is preserved exactly.
// ---------------------------------------------------------------------------
__global__ __launch_bounds__(256) void k_topk(const float2* __restrict__ pxy,
                                              const float* __restrict__ maskf,
                                              int* __restrict__ nbr,
                                              int* __restrict__ degi) {
  __shared__ float2 pls[NN];            // 8 KB
  __shared__ u64 lst[16][64];           // 8 KB contender lists
  __shared__ int dcnt[16];
  __shared__ int ccnt[16];

  const int b = blockIdx.x;
  const int t = threadIdx.x;
  const int rl = t >> 4;                // row within block, 0..15
  const int s  = t & 15;                // sublane within row, 0..15
  const int row = blockIdx.y * 16 + rl;
  const size_t r = (size_t)b * NN + row;

  {
    const float4* src = (const float4*)(pxy + (size_t)b * NN);
    float4* dst = (float4*)pls;
    dst[t] = src[t];
    dst[t + 256] = src[t + 256];
  }
  if (s == 0) { dcnt[rl] = 0; ccnt[rl] = 0; }
  __syncthreads();

  const bool valid = (maskf[r] != 0.f);
  const float2 pi = pls[row];
  const float xi = pi.x, yi = pi.y;

  // ---- pass 1: bucket 64 own candidates into 8 packed u64 words ----
  u64 cc[8];
  if (valid) {
#pragma unroll
    for (int q = 0; q < 8; ++q) {
      unsigned lo = 0, hiw = 0;
#pragma unroll
      for (int u = 0; u < 4; ++u) {
        const int i = q * 8 + u;
        const int j = s * 64 + ((i + s) & 63);
        const float2 p = pls[j];
        const float dx = __fsub_rn(xi, p.x);
        const float dy = __fsub_rn(yi, p.y);
        const float d2 = __fadd_rn(__fmul_rn(dx, dx), __fmul_rn(dy, dy));
        lo |= (unsigned)d2b7(d2) << (8 * u);
      }
#pragma unroll
      for (int u = 0; u < 4; ++u) {
        const int i = q * 8 + 4 + u;
        const int j = s * 64 + ((i + s) & 63);
        const float2 p = pls[j];
        const float dx = __fsub_rn(xi, p.x);
        const float dy = __fsub_rn(yi, p.y);
        const float d2 = __fadd_rn(__fmul_rn(dx, dx), __fmul_rn(dy, dy));
        hiw |= (unsigned)d2b7(d2) << (8 * u);
      }
      cc[q] = (u64)lo | ((u64)hiw << 32);
    }
    // self-patch: exactly one lane owns `row`; set its byte to 127
    if (s == (row >> 6)) {
      const int isf = ((row & 63) - s) & 63;
      const u64 pbit = 0x7Full << (8 * (isf & 7));
#pragma unroll
      for (int q = 0; q < 8; ++q) if (q == (isf >> 3)) cc[q] |= pbit;
    }
  } else {
#pragma unroll
    for (int q = 0; q < 8; ++q) cc[q] = 0x7F7F7F7F7F7F7F7Full;
  }

  // ---- binary search for B* = min X with cnt(<=X) >= 16; ndef = cnt(<B*) ----
  int lo = 0, hi = 126, ndef = 0;
#pragma unroll
  for (int it = 0; it < 7; ++it) {
    const int mid = (lo + hi) >> 1;
    const u64 K = (u64)(unsigned)(128 + mid) * 0x0101010101010101ull;
    int c = 0;
#pragma unroll
    for (int q = 0; q < 8; ++q)
      c += __popcll((K - cc[q]) & 0x8080808080808080ull);
#pragma unroll
    for (int off = 1; off < 16; off <<= 1)
      c += __shfl_xor(c, off, 16);
    if (c >= 16) hi = mid;
    else { lo = mid + 1; ndef = c; }
  }
  const int Bstar = lo;
  int need = 16 - ndef;

  // ---- pass 2: SWAR classify cached bytes; only hits do real work ----
  int cem = 0;
  if (valid) {
    const u64 Klo = (u64)(unsigned)(127 + Bstar) * 0x0101010101010101ull; // byte < B*
    const u64 Khi = Klo + 0x0101010101010101ull;                          // byte <= B*
#pragma unroll
    for (int q = 0; q < 8; ++q) {
      const u64 w = cc[q];
      const u64 mLE = (Khi - w) & 0x8080808080808080ull;
      if (mLE) {
        const u64 mLT = (Klo - w) & 0x8080808080808080ull;
#pragma unroll
        for (int u = 0; u < 8; ++u) {
          const u64 bit = 0x80ull << (8 * u);
          if (mLE & bit) {
            const int j = s * 64 + ((q * 8 + u + s) & 63);
            if (mLT & bit) {               // definite top-16 member
              const int sl = atomicAdd(&dcnt[rl], 1);
              nbr[r * KK + sl] = j;
              atomicAdd(&degi[b * NN + j], 1);
            } else {                        // contender (bucket == B*)
              const float2 p = pls[j];
              const float dx = __fsub_rn(xi, p.x);
              const float dy = __fsub_rn(yi, p.y);
              const float d2 = __fadd_rn(__fmul_rn(dx, dx), __fmul_rn(dy, dy));
              const int sl = atomicAdd(&ccnt[rl], 1);
              if (sl < 64) lst[rl][sl] = ((u64)__float_as_uint(d2) << 10) | (unsigned)j;
              ++cem;
            }
          }
        }
      }
    }
  }
  __syncthreads();

  // ---- contender extraction: iterated exact-min over packed keys ----
  int cn = cem;
#pragma unroll
  for (int off = 1; off < 16; off <<= 1) cn += __shfl_xor(cn, off, 16);
  cn = cn < 64 ? cn : 64;
  if (!valid) { cn = 0; need = 0; }

  u64 k0 = (s      < cn) ? lst[rl][s]      : ~0ull;
  u64 k1 = (s + 16 < cn) ? lst[rl][s + 16] : ~0ull;
  u64 k2 = (s + 32 < cn) ? lst[rl][s + 32] : ~0ull;
  u64 k3 = (s + 48 < cn) ? lst[rl][s + 48] : ~0ull;

  int e = 0;
  while (__any(e < need)) {
    u64 m01 = k0 < k1 ? k0 : k1;
    u64 m23 = k2 < k3 ? k2 : k3;
    u64 m = m01 < m23 ? m01 : m23;
#pragma unroll
    for (int off = 1; off < 16; off <<= 1) {
      const u64 o = __shfl_xor(m, off, 16);
      m = o < m ? o : m;
    }
    if (e < need) {
      if (k0 == m) k0 = ~0ull;
      else if (k1 == m) k1 = ~0ull;
      else if (k2 == m) k2 = ~0ull;
      else if (k3 == m) k3 = ~0ull;
      if (s == 0) {
        const int j = (int)(m & (u64)(NN - 1));
        nbr[r * KK + ndef + e] = j;
        atomicAdd(&degi[b * NN + j], 1);
      }
    }
    ++e;
  }
}

// ---------------------------------------------------------------------------
// K3: per-batch scan + dinv + reverse-edge fill (LDS cursors), one block
// per batch. cur[r] = global START of r's segment; rev[pos]=(src, s_src).
// ---------------------------------------------------------------------------
__global__ __launch_bounds__(1024) void k_graph(const int* __restrict__ degi,
                                                const float* __restrict__ maskf,
                                                const int* __restrict__ nbr,
                                                int* __restrict__ cur,
                                                float* __restrict__ dinv,
                                                int2* __restrict__ rev) {
  __shared__ int wsum[16];
  __shared__ int lcur[NN];
  const int b = blockIdx.x, t = threadIdx.x;
  const int lane = t & 63, w = t >> 6;
  const int r = b * NN + t;
  const int d = degi[r];
  int x = d;
#pragma unroll
  for (int off = 1; off < 64; off <<= 1) {
    int y = __shfl_up(x, off, 64);
    if (lane >= off) x += y;
  }
  if (lane == 63) wsum[w] = x;

  const float m = maskf[r];
  const float deg = (float)d + 2.f * m;
  const float dv = (deg > 0.f) ? (1.f / sqrtf(deg)) : 0.f;
  dinv[r] = dv;
  const float sv = dv * m;

  __syncthreads();
  if (w == 0) {
    int v = (lane < 16) ? wsum[lane] : 0;
#pragma unroll
    for (int off = 1; off < 16; off <<= 1) {
      int y = __shfl_up(v, off, 64);
      if (lane >= off) v += y;
    }
    if (lane < 16) wsum[lane] = v;
  }
  __syncthreads();
  const int start = b * (NN * KK) + (w ? wsum[w - 1] : 0) + x - d;  // exclusive
  lcur[t] = start;
  cur[r] = start;
  __syncthreads();

  if (m != 0.f) {
    const int sb = __float_as_int(sv);
    const int4* n4 = (const int4*)(nbr + (size_t)r * KK);
#pragma unroll
    for (int q = 0; q < 4; ++q) {
      int4 v = n4[q];
      int nb[4] = {v.x, v.y, v.z, v.w};
#pragma unroll
      for (int u = 0; u < 4; ++u) {
        const int pos = atomicAdd(&lcur[nb[u]], 1);
        rev[pos] = make_int2(r, sb);
      }
    }
  }
}

// ---------------------------------------------------------------------------
// K4: chunked-LDS GCN gather. Grid (batch, 8 channel-chunks of 16), block =
// 1024 nodes. Stage y[b][:, c0:c0+16] (64 KB) into LDS with per-row float4
// rotation swizzle (slot = row*4 + ((chunk+row)&3)) so random-row b128
// gathers spread across all 32 banks. Each node gathers its CSR segment
// from LDS (69 TB/s) instead of L3. h = tanh(di*agg + 2di^2*y + b).
// ---------------------------------------------------------------------------
__global__ __launch_bounds__(1024) void k_gcnc(const float* __restrict__ y,
                                               const float* __restrict__ dinv,
                                               const int* __restrict__ degi,
                                               const int* __restrict__ cur,
                                               const int2* __restrict__ rev,
                                               const float* __restrict__ bias,
                                               float* __restrict__ hout) {
  __shared__ float4 ych[NN * 4];   // 64 KB, swizzled
  const int b = blockIdx.x;
  const int c0 = blockIdx.y * 16;
  const int t = threadIdx.x;

  {
    const float* yb = y + (size_t)b * NN * HH + c0;
#pragma unroll
    for (int k = 0; k < 4; ++k) {
      const int idx = t + k * 1024;          // float4 index 0..4095
      const int rowq = idx >> 2, cq = idx & 3;
      ych[rowq * 4 + ((cq + rowq) & 3)] =
          *(const float4*)(yb + (size_t)rowq * HH + cq * 4);
    }
  }
  __syncthreads();

  const int r = b * NN + t;
  const int cnt = degi[r];
  const int off = cur[r];
  const float di = dinv[r];

  float4 a0 = make_float4(0.f, 0.f, 0.f, 0.f);
  float4 a1 = a0, a2 = a0, a3 = a0;
  for (int e = 0; e < cnt; ++e) {
    const int2 ed = rev[off + e];
    const int sl = ed.x & (NN - 1);
    const float se = __int_as_float(ed.y);
    const int base = sl * 4;
    const float4 y0 = ych[base + (sl & 3)];
    const float4 y1 = ych[base + ((sl + 1) & 3)];
    const float4 y2 = ych[base + ((sl + 2) & 3)];
    const float4 y3 = ych[base + ((sl + 3) & 3)];
    a0.x += se * y0.x; a0.y += se * y0.y; a0.z += se * y0.z; a0.w += se * y0.w;
    a1.x += se * y1.x; a1.y += se * y1.y; a1.z += se * y1.z; a1.w += se * y1.w;
    a2.x += se * y2.x; a2.y += se * y2.y; a2.z += se * y2.z; a2.w += se * y2.w;
    a3.x += se * y3.x; a3.y += se * y3.y; a3.z += se * y3.z; a3.w += se * y3.w;
  }

  const int nb4 = t * 4;
  const float4 s0 = ych[nb4 + (t & 3)];
  const float4 s1 = ych[nb4 + ((t + 1) & 3)];
  const float4 s2 = ych[nb4 + ((t + 2) & 3)];
  const float4 s3 = ych[nb4 + ((t + 3) & 3)];
  const float4 b0 = *(const float4*)(bias + c0);
  const float4 b1 = *(const float4*)(bias + c0 + 4);
  const float4 b2 = *(const float4*)(bias + c0 + 8);
  const float4 b3 = *(const float4*)(bias + c0 + 12);
  const float t2 = 2.f * di * di;

  float4 h0, h1, h2, h3;
  h0.x = tanhf(di * a0.x + t2 * s0.x + b0.x);
  h0.y = tanhf(di * a0.y + t2 * s0.y + b0.y);
  h0.z = tanhf(di * a0.z + t2 * s0.z + b0.z);
  h0.w = tanhf(di * a0.w + t2 * s0.w + b0.w);
  h1.x = tanhf(di * a1.x + t2 * s1.x + b1.x);
  h1.y = tanhf(di * a1.y + t2 * s1.y + b1.y);
  h1.z = tanhf(di * a1.z + t2 * s1.z + b1.z);
  h1.w = tanhf(di * a1.w + t2 * s1.w + b1.w);
  h2.x = tanhf(di * a2.x + t2 * s2.x + b2.x);
  h2.y = tanhf(di * a2.y + t2 * s2.y + b2.y);
  h2.z = tanhf(di * a2.z + t2 * s2.z + b2.z);
  h2.w = tanhf(di * a2.w + t2 * s2.w + b2.w);
  h3.x = tanhf(di * a3.x + t2 * s3.x + b3.x);
  h3.y = tanhf(di * a3.y + t2 * s3.y + b3.y);
  h3.z = tanhf(di * a3.z + t2 * s3.z + b3.z);
  h3.w = tanhf(di * a3.w + t2 * s3.w + b3.w);

  float4* hrow = (float4*)(hout + (size_t)r * HH + c0);
  hrow[0] = h0; hrow[1] = h1; hrow[2] = h2; hrow[3] = h3;
}

// ---------------------------------------------------------------------------
// K5: out = (h @ W_out + b_out) * maskf
// ---------------------------------------------------------------------------
__global__ __launch_bounds__(256) void k_out(const float* __restrict__ h,
                                             const float* __restrict__ Wo,
                                             const float* __restrict__ bo,
                                             const float* __restrict__ maskf,
                                             float* __restrict__ out) {
  __shared__ float Ws[HH * OD];
  __shared__ float bs[OD];
  const int t = threadIdx.x;
  for (int q = t; q < HH * OD / 4; q += 256) ((float4*)Ws)[q] = ((const float4*)Wo)[q];
  if (t < OD) bs[t] = bo[t];
  __syncthreads();

  const size_t r = (size_t)blockIdx.x * 256 + t;
  const float4* hrow = (const float4*)(h + r * HH);
  float acc[OD];
#pragma unroll
  for (int o = 0; o < OD; ++o) acc[o] = 0.f;

#pragma unroll 4
  for (int q = 0; q < HH / 4; ++q) {
    const float4 hv = hrow[q];
    const float* w = &Ws[(q * 4) * OD];
#pragma unroll
    for (int o = 0; o < OD; ++o) acc[o] += hv.x * w[o];
#pragma unroll
    for (int o = 0; o < OD; ++o) acc[o] += hv.y * w[OD + o];
#pragma unroll
    for (int o = 0; o < OD; ++o) acc[o] += hv.z * w[2 * OD + o];
#pragma unroll
    for (int o = 0; o < OD; ++o) acc[o] += hv.w * w[3 * OD + o];
  }
  const float mf = maskf[r];
  float4* orow = (float4*)(out + r * OD);
  orow[0] = make_float4((acc[0] + bs[0]) * mf, (acc[1] + bs[1]) * mf,
                        (acc[2] + bs[2]) * mf, (acc[3] + bs[3]) * mf);
  orow[1] = make_float4((acc[4] + bs[4]) * mf, (acc[5] + bs[5]) * mf,
                        (acc[6] + bs[6]) * mf, (acc[7] + bs[7]) * mf);
}

// ---------------------------------------------------------------------------
extern "C" void kernel_launch(void* const* d_in, const int* in_sizes, int n_in,
                              void* d_out, int out_size, void* d_ws, size_t ws_size,
                              hipStream_t stream) {
  (void)in_sizes; (void)n_in; (void)out_size; (void)ws_size;
  const float* obs = (const float*)d_in[0];
  const float* W1  = (const float*)d_in[1];
  const float* b1  = (const float*)d_in[2];
  const float* W2  = (const float*)d_in[3];
  const float* b2  = (const float*)d_in[4];
  const float* Wo  = (const float*)d_in[5];
  const float* bo  = (const float*)d_in[6];
  float* out = (float*)d_out;

  char* ws = (char*)d_ws;
  float* maskf = (float*)(ws);                             // 128 KB
  int*   degi  = (int*)  (ws + (size_t)(128 << 10));       // 128 KB
  float* dinv  = (float*)(ws + (size_t)(256 << 10));       // 128 KB
  int*   cur   = (int*)  (ws + (size_t)(384 << 10));       // 128 KB
  float2* pxy  = (float2*)(ws + (size_t)(512 << 10));      // 256 KB
  int*   nbr   = (int*)  (ws + (size_t)(1u << 20));        // 2 MB
  int2*  rev   = (int2*) (ws + (size_t)(3u << 20));        // 4 MB
  float* ybuf  = (float*)(ws + (size_t)(7u << 20));        // 16 MB
  float* hbuf  = (float*)(ws + (size_t)(23u << 20));       // 16 MB

  k_gemm<DD, true><<<M_TOT / 64, 512, 0, stream>>>(obs, W1, ybuf, maskf, degi, pxy);
  k_topk<<<dim3(BB, NN / 16), 256, 0, stream>>>(pxy, maskf, nbr, degi);
  k_graph<<<BB, 1024, 0, stream>>>(degi, maskf, nbr, cur, dinv, rev);
  k_gcnc<<<dim3(BB, HH / 16), 1024, 0, stream>>>(ybuf, dinv, degi, cur, rev, b1, hbuf);
  k_gemm<HH, false><<<M_TOT / 64, 512, 0, stream>>>(hbuf, W2, ybuf, nullptr, nullptr, nullptr);
  k_gcnc<<<dim3(BB, HH / 16), 1024, 0, stream>>>(ybuf, dinv, degi, cur, rev, b2, hbuf);
  k_out<<<M_TOT / 256, 256, 0, stream>>>(hbuf, Wo, bo, maskf, out);
}

// Round 9
// 135.081 us; speedup vs baseline: 1.2588x; 1.0239x over previous
//
#include <hip/hip_runtime.h>
#include <hip/hip_bf16.h>
#include <math.h>

#define BB 32
#define NN 1024
#define DD 64
#define HH 128
#define KK 16
#define OD 8
#define M_TOT (BB*NN)

typedef unsigned long long u64;

// 7-bit bucket: clamp((f32bits >> 22) - 200, 0, 126); self uses 127.
// Strictly monotone in d2 (d2 >= 0). All bucket bytes <= 127 -> the SWAR
// subtracts below are borrow-free per byte (K bytes >= 128) and exact in u64.
static __device__ __forceinline__ int d2b7(float d2) {
  int v = (int)(__float_as_uint(d2) >> 22) - 200;
  v = v < 0 ? 0 : v;
  return v > 126 ? 126 : v;
}

// ---------------------------------------------------------------------------
// K1: Y = X @ W (64 rows x 128 cols / block, 512 thr, 4x4 acc/thread).
// EMIT_MASK: during X staging also compute mask = any(row != 0), emit
// maskf / pxy (inf-masked x,y) / degi = 0.
// ---------------------------------------------------------------------------
template <int CIN, bool EMIT_MASK>
__global__ __launch_bounds__(512) void k_gemm(const float* __restrict__ X,
                                              const float* __restrict__ W,
                                              float* __restrict__ Y,
                                              float* __restrict__ maskf,
                                              int* __restrict__ degi,
                                              float2* __restrict__ pxy) {
  __shared__ float Ws[32 * HH];      // 16 KB
  __shared__ float Xt[32 * 68];      // 8.5 KB, Xt[k][row]
  __shared__ int rowflag[64];
  __shared__ float2 praw[64];
  const int t = threadIdx.x;
  const size_t rowbase = (size_t)blockIdx.x * 64;

  if (EMIT_MASK && t < 64) rowflag[t] = 0;

  const int c4 = (t & 31) * 4;
  const int r4 = (t >> 5) * 4;

  float acc[4][4] = {{0.f}};

  for (int k0 = 0; k0 < CIN; k0 += 32) {
    __syncthreads();
    {
      const float4* Wt4 = (const float4*)(W + (size_t)k0 * HH);
      ((float4*)Ws)[t]       = Wt4[t];
      ((float4*)Ws)[t + 512] = Wt4[t + 512];
    }
    {
      const int row = t >> 3;        // 0..63
      const int kq  = t & 7;         // 0..7
      float4 v = *(const float4*)(X + (rowbase + row) * CIN + k0 + kq * 4);
      if (EMIT_MASK) {
        if (v.x != 0.f || v.y != 0.f || v.z != 0.f || v.w != 0.f)
          rowflag[row] = 1;          // benign race: all writers store 1
        if (k0 == 0 && kq == 0) praw[row] = make_float2(v.x, v.y);
      }
      Xt[(kq * 4 + 0) * 68 + row] = v.x;
      Xt[(kq * 4 + 1) * 68 + row] = v.y;
      Xt[(kq * 4 + 2) * 68 + row] = v.z;
      Xt[(kq * 4 + 3) * 68 + row] = v.w;
    }
    __syncthreads();
#pragma unroll
    for (int k = 0; k < 32; ++k) {
      const float4 xa = *(const float4*)&Xt[k * 68 + r4];
      const float4 wb = *(const float4*)&Ws[k * HH + c4];
      acc[0][0] += xa.x * wb.x; acc[0][1] += xa.x * wb.y; acc[0][2] += xa.x * wb.z; acc[0][3] += xa.x * wb.w;
      acc[1][0] += xa.y * wb.x; acc[1][1] += xa.y * wb.y; acc[1][2] += xa.y * wb.z; acc[1][3] += xa.y * wb.w;
      acc[2][0] += xa.z * wb.x; acc[2][1] += xa.z * wb.y; acc[2][2] += xa.z * wb.z; acc[2][3] += xa.z * wb.w;
      acc[3][0] += xa.w * wb.x; acc[3][1] += xa.w * wb.y; acc[3][2] += xa.w * wb.z; acc[3][3] += xa.w * wb.w;
    }
  }
#pragma unroll
  for (int i = 0; i < 4; ++i)
    *(float4*)(Y + (rowbase + r4 + i) * HH + c4) =
        make_float4(acc[i][0], acc[i][1], acc[i][2], acc[i][3]);

  if (EMIT_MASK && t < 64) {
    const size_t gr = rowbase + t;
    const int any = rowflag[t];
    maskf[gr] = any ? 1.f : 0.f;
    degi[gr] = 0;
    const float inf = __builtin_inff();
    pxy[gr] = any ? praw[t] : make_float2(inf, inf);
  }
}

// ---------------------------------------------------------------------------
// K2: exact 16-NN set per row. 16 lanes/row, 16 rows/block. Lane s owns
// candidates [s*64, s*64+64), read as 32 float4 pair-loads with rotation
// p=(i+s)&31 (<=2-way bank conflicts = free; cross-row-groups broadcast).
// Bucket bytes packed into 8 u64 VGPRs; self handled by a single post-loop
// byte patch (d2_self = 0 -> byte 0 -> |0x7F = 127). Cutoff B* via 7-probe
// binary search with u64-SWAR popcount. Pass 2 SWAR-classifies registers;
// contenders (== B*) carry exact packed keys (d2 bits << 10 | idx) so JAX's
// lowest-index-on-tie is preserved exactly.
// ---------------------------------------------------------------------------
__global__ __launch_bounds__(256) void k_topk(const float2* __restrict__ pxy,
                                              const float* __restrict__ maskf,
                                              int* __restrict__ nbr,
                                              int* __restrict__ degi) {
  __shared__ float2 pls[NN];            // 8 KB
  __shared__ u64 lst[16][64];           // 8 KB contender lists
  __shared__ int dcnt[16];
  __shared__ int ccnt[16];

  const int b = blockIdx.x;
  const int t = threadIdx.x;
  const int rl = t >> 4;                // row within block, 0..15
  const int s  = t & 15;                // sublane within row, 0..15
  const int row = blockIdx.y * 16 + rl;
  const size_t r = (size_t)b * NN + row;

  {
    const float4* src = (const float4*)(pxy + (size_t)b * NN);
    float4* dst = (float4*)pls;
    dst[t] = src[t];
    dst[t + 256] = src[t + 256];
  }
  if (s == 0) { dcnt[rl] = 0; ccnt[rl] = 0; }
  __syncthreads();

  const bool valid = (maskf[r] != 0.f);
  const float2 pi = pls[row];
  const float xi = pi.x, yi = pi.y;
  const float4* pls4 = (const float4*)pls;

  // ---- pass 1: bucket 64 own candidates (32 pair-loads) into 8 u64 ----
  u64 cc[8];
  if (valid) {
#pragma unroll
    for (int q = 0; q < 8; ++q) {
      unsigned lo = 0, hiw = 0;
#pragma unroll
      for (int ii = 0; ii < 4; ++ii) {
        const int i = q * 4 + ii;
        const int p = (i + s) & 31;
        const float4 pr = pls4[s * 32 + p];   // candidates 2p, 2p+1 of this lane
        const float dx0 = __fsub_rn(xi, pr.x), dy0 = __fsub_rn(yi, pr.y);
        const float d20 = __fadd_rn(__fmul_rn(dx0, dx0), __fmul_rn(dy0, dy0));
        const float dx1 = __fsub_rn(xi, pr.z), dy1 = __fsub_rn(yi, pr.w);
        const float d21 = __fadd_rn(__fmul_rn(dx1, dx1), __fmul_rn(dy1, dy1));
        const unsigned pb = (unsigned)d2b7(d20) | ((unsigned)d2b7(d21) << 8);
        if (ii == 0) lo |= pb;
        else if (ii == 1) lo |= pb << 16;
        else if (ii == 2) hiw |= pb;
        else hiw |= pb << 16;
      }
      cc[q] = (u64)lo | ((u64)hiw << 32);
    }
    // self-patch: d2(self)=0 -> its byte is 0; OR 0x7F makes it exactly 127.
    if (s == (row >> 6)) {
      const int c = row & 63;
      const int i = ((c >> 1) - s) & 31;      // pair-iter that produced self
      const int q_ = i >> 2;
      const int u_ = 2 * (i & 3) + (c & 1);   // byte position within word
      const u64 pb = 0x7Full << (8 * u_);
#pragma unroll
      for (int q = 0; q < 8; ++q) if (q == q_) cc[q] |= pb;
    }
  } else {
#pragma unroll
    for (int q = 0; q < 8; ++q) cc[q] = 0x7F7F7F7F7F7F7F7Full;
  }

  // ---- binary search for B* = min X with cnt(<=X) >= 16; ndef = cnt(<B*) ----
  int lo = 0, hi = 126, ndef = 0;
#pragma unroll
  for (int it = 0; it < 7; ++it) {
    const int mid = (lo + hi) >> 1;
    const u64 K = (u64)(unsigned)(128 + mid) * 0x0101010101010101ull;
    int c = 0;
#pragma unroll
    for (int q = 0; q < 8; ++q)
      c += __popcll((K - cc[q]) & 0x8080808080808080ull);
#pragma unroll
    for (int off = 1; off < 16; off <<= 1)
      c += __shfl_xor(c, off, 16);
    if (c >= 16) hi = mid;
    else { lo = mid + 1; ndef = c; }
  }
  const int Bstar = lo;
  int need = 16 - ndef;

  // ---- pass 2: SWAR classify cached bytes; only hits do real work ----
  int cem = 0;
  if (valid) {
    const u64 Klo = (u64)(unsigned)(127 + Bstar) * 0x0101010101010101ull; // byte < B*
    const u64 Khi = Klo + 0x0101010101010101ull;                          // byte <= B*
#pragma unroll
    for (int q = 0; q < 8; ++q) {
      const u64 w = cc[q];
      const u64 mLE = (Khi - w) & 0x8080808080808080ull;
      if (mLE) {
        const u64 mLT = (Klo - w) & 0x8080808080808080ull;
#pragma unroll
        for (int u = 0; u < 8; ++u) {
          const u64 bit = 0x80ull << (8 * u);
          if (mLE & bit) {
            const int i = q * 4 + (u >> 1);
            const int j = s * 64 + (((i + s) & 31) << 1) + (u & 1);
            if (mLT & bit) {               // definite top-16 member
              const int sl = atomicAdd(&dcnt[rl], 1);
              nbr[r * KK + sl] = j;
              atomicAdd(&degi[b * NN + j], 1);
            } else {                        // contender (bucket == B*)
              const float2 p = pls[j];
              const float dx = __fsub_rn(xi, p.x);
              const float dy = __fsub_rn(yi, p.y);
              const float d2 = __fadd_rn(__fmul_rn(dx, dx), __fmul_rn(dy, dy));
              const int sl = atomicAdd(&ccnt[rl], 1);
              if (sl < 64) lst[rl][sl] = ((u64)__float_as_uint(d2) << 10) | (unsigned)j;
              ++cem;
            }
          }
        }
      }
    }
  }
  __syncthreads();

  // ---- contender extraction: iterated exact-min over packed keys ----
  int cn = cem;
#pragma unroll
  for (int off = 1; off < 16; off <<= 1) cn += __shfl_xor(cn, off, 16);
  cn = cn < 64 ? cn : 64;
  if (!valid) { cn = 0; need = 0; }

  u64 k0 = (s      < cn) ? lst[rl][s]      : ~0ull;
  u64 k1 = (s + 16 < cn) ? lst[rl][s + 16] : ~0ull;
  u64 k2 = (s + 32 < cn) ? lst[rl][s + 32] : ~0ull;
  u64 k3 = (s + 48 < cn) ? lst[rl][s + 48] : ~0ull;

  int e = 0;
  while (__any(e < need)) {
    u64 m01 = k0 < k1 ? k0 : k1;
    u64 m23 = k2 < k3 ? k2 : k3;
    u64 m = m01 < m23 ? m01 : m23;
#pragma unroll
    for (int off = 1; off < 16; off <<= 1) {
      const u64 o = __shfl_xor(m, off, 16);
      m = o < m ? o : m;
    }
    if (e < need) {
      if (k0 == m) k0 = ~0ull;
      else if (k1 == m) k1 = ~0ull;
      else if (k2 == m) k2 = ~0ull;
      else if (k3 == m) k3 = ~0ull;
      if (s == 0) {
        const int j = (int)(m & (u64)(NN - 1));
        nbr[r * KK + ndef + e] = j;
        atomicAdd(&degi[b * NN + j], 1);
      }
    }
    ++e;
  }
}

// ---------------------------------------------------------------------------
// K3: per-batch scan + dinv + reverse-edge fill (LDS cursors), one block
// per batch. cur[r] = global START of r's segment; rev[pos]=(src, s_src).
// ---------------------------------------------------------------------------
__global__ __launch_bounds__(1024) void k_graph(const int* __restrict__ degi,
                                                const float* __restrict__ maskf,
                                                const int* __restrict__ nbr,
                                                int* __restrict__ cur,
                                                float* __restrict__ dinv,
                                                int2* __restrict__ rev) {
  __shared__ int wsum[16];
  __shared__ int lcur[NN];
  const int b = blockIdx.x, t = threadIdx.x;
  const int lane = t & 63, w = t >> 6;
  const int r = b * NN + t;
  const int d = degi[r];
  int x = d;
#pragma unroll
  for (int off = 1; off < 64; off <<= 1) {
    int y = __shfl_up(x, off, 64);
    if (lane >= off) x += y;
  }
  if (lane == 63) wsum[w] = x;

  const float m = maskf[r];
  const float deg = (float)d + 2.f * m;
  const float dv = (deg > 0.f) ? (1.f / sqrtf(deg)) : 0.f;
  dinv[r] = dv;
  const float sv = dv * m;

  __syncthreads();
  if (w == 0) {
    int v = (lane < 16) ? wsum[lane] : 0;
#pragma unroll
    for (int off = 1; off < 16; off <<= 1) {
      int y = __shfl_up(v, off, 64);
      if (lane >= off) v += y;
    }
    if (lane < 16) wsum[lane] = v;
  }
  __syncthreads();
  const int start = b * (NN * KK) + (w ? wsum[w - 1] : 0) + x - d;  // exclusive
  lcur[t] = start;
  cur[r] = start;
  __syncthreads();

  if (m != 0.f) {
    const int sb = __float_as_int(sv);
    const int4* n4 = (const int4*)(nbr + (size_t)r * KK);
#pragma unroll
    for (int q = 0; q < 4; ++q) {
      int4 v = n4[q];
      int nb[4] = {v.x, v.y, v.z, v.w};
#pragma unroll
      for (int u = 0; u < 4; ++u) {
        const int pos = atomicAdd(&lcur[nb[u]], 1);
        rev[pos] = make_int2(r, sb);
      }
    }
  }
}

// ---------------------------------------------------------------------------
// K4: chunked-LDS GCN gather. Grid (batch, 16 channel-chunks of 8), block =
// 1024 nodes. Stage y[b][:, c0:c0+8] (32 KB -> 2 blocks/CU, full thread
// occupancy) with per-row float4 rotation swizzle (slot = row*2 +
// ((chunk+row)&1)). Each node gathers its CSR segment from LDS.
// h = tanh(di*agg + 2di^2*y + b).
// ---------------------------------------------------------------------------
__global__ __launch_bounds__(1024) void k_gcnc(const float* __restrict__ y,
                                               const float* __restrict__ dinv,
                                               const int* __restrict__ degi,
                                               const int* __restrict__ cur,
                                               const int2* __restrict__ rev,
                                               const float* __restrict__ bias,
                                               float* __restrict__ hout) {
  __shared__ float4 ych[NN * 2];   // 32 KB, swizzled
  const int b = blockIdx.x;
  const int c0 = blockIdx.y * 8;
  const int t = threadIdx.x;

  {
    const float* yb = y + (size_t)b * NN * HH + c0;
#pragma unroll
    for (int k = 0; k < 2; ++k) {
      const int idx = t + k * 1024;          // float4 index 0..2047
      const int rowq = idx >> 1, cq = idx & 1;
      ych[rowq * 2 + ((cq + rowq) & 1)] =
          *(const float4*)(yb + (size_t)rowq * HH + cq * 4);
    }
  }
  __syncthreads();

  const int r = b * NN + t;
  const int cnt = degi[r];
  const int off = cur[r];
  const float di = dinv[r];

  float4 a0 = make_float4(0.f, 0.f, 0.f, 0.f);
  float4 a1 = a0;
  for (int e = 0; e < cnt; ++e) {
    const int2 ed = rev[off + e];
    const int sl = ed.x & (NN - 1);
    const float se = __int_as_float(ed.y);
    const int base = sl * 2;
    const float4 y0 = ych[base + (sl & 1)];          // cq 0
    const float4 y1 = ych[base + ((sl + 1) & 1)];    // cq 1
    a0.x += se * y0.x; a0.y += se * y0.y; a0.z += se * y0.z; a0.w += se * y0.w;
    a1.x += se * y1.x; a1.y += se * y1.y; a1.z += se * y1.z; a1.w += se * y1.w;
  }

  const int nb2 = t * 2;
  const float4 s0 = ych[nb2 + (t & 1)];
  const float4 s1 = ych[nb2 + ((t + 1) & 1)];
  const float4 b0 = *(const float4*)(bias + c0);
  const float4 b1 = *(const float4*)(bias + c0 + 4);
  const float t2 = 2.f * di * di;

  float4 h0, h1;
  h0.x = tanhf(di * a0.x + t2 * s0.x + b0.x);
  h0.y = tanhf(di * a0.y + t2 * s0.y + b0.y);
  h0.z = tanhf(di * a0.z + t2 * s0.z + b0.z);
  h0.w = tanhf(di * a0.w + t2 * s0.w + b0.w);
  h1.x = tanhf(di * a1.x + t2 * s1.x + b1.x);
  h1.y = tanhf(di * a1.y + t2 * s1.y + b1.y);
  h1.z = tanhf(di * a1.z + t2 * s1.z + b1.z);
  h1.w = tanhf(di * a1.w + t2 * s1.w + b1.w);

  float4* hrow = (float4*)(hout + (size_t)r * HH + c0);
  hrow[0] = h0; hrow[1] = h1;
}

// ---------------------------------------------------------------------------
// K5: out = (h @ W_out + b_out) * maskf
// ---------------------------------------------------------------------------
__global__ __launch_bounds__(256) void k_out(const float* __restrict__ h,
                                             const float* __restrict__ Wo,
                                             const float* __restrict__ bo,
                                             const float* __restrict__ maskf,
                                             float* __restrict__ out) {
  __shared__ float Ws[HH * OD];
  __shared__ float bs[OD];
  const int t = threadIdx.x;
  for (int q = t; q < HH * OD / 4; q += 256) ((float4*)Ws)[q] = ((const float4*)Wo)[q];
  if (t < OD) bs[t] = bo[t];
  __syncthreads();

  const size_t r = (size_t)blockIdx.x * 256 + t;
  const float4* hrow = (const float4*)(h + r * HH);
  float acc[OD];
#pragma unroll
  for (int o = 0; o < OD; ++o) acc[o] = 0.f;

#pragma unroll 4
  for (int q = 0; q < HH / 4; ++q) {
    const float4 hv = hrow[q];
    const float* w = &Ws[(q * 4) * OD];
#pragma unroll
    for (int o = 0; o < OD; ++o) acc[o] += hv.x * w[o];
#pragma unroll
    for (int o = 0; o < OD; ++o) acc[o] += hv.y * w[OD + o];
#pragma unroll
    for (int o = 0; o < OD; ++o) acc[o] += hv.z * w[2 * OD + o];
#pragma unroll
    for (int o = 0; o < OD; ++o) acc[o] += hv.w * w[3 * OD + o];
  }
  const float mf = maskf[r];
  float4* orow = (float4*)(out + r * OD);
  orow[0] = make_float4((acc[0] + bs[0]) * mf, (acc[1] + bs[1]) * mf,
                        (acc[2] + bs[2]) * mf, (acc[3] + bs[3]) * mf);
  orow[1] = make_float4((acc[4] + bs[4]) * mf, (acc[5] + bs[5]) * mf,
                        (acc[6] + bs[6]) * mf, (acc[7] + bs[7]) * mf);
}

// ---------------------------------------------------------------------------
extern "C" void kernel_launch(void* const* d_in, const int* in_sizes, int n_in,
                              void* d_out, int out_size, void* d_ws, size_t ws_size,
                              hipStream_t stream) {
  (void)in_sizes; (void)n_in; (void)out_size; (void)ws_size;
  const float* obs = (const float*)d_in[0];
  const float* W1  = (const float*)d_in[1];
  const float* b1  = (const float*)d_in[2];
  const float* W2  = (const float*)d_in[3];
  const float* b2  = (const float*)d_in[4];
  const float* Wo  = (const float*)d_in[5];
  const float* bo  = (const float*)d_in[6];
  float* out = (float*)d_out;

  char* ws = (char*)d_ws;
  float* maskf = (float*)(ws);                             // 128 KB
  int*   degi  = (int*)  (ws + (size_t)(128 << 10));       // 128 KB
  float* dinv  = (float*)(ws + (size_t)(256 << 10));       // 128 KB
  int*   cur   = (int*)  (ws + (size_t)(384 << 10));       // 128 KB
  float2* pxy  = (float2*)(ws + (size_t)(512 << 10));      // 256 KB
  int*   nbr   = (int*)  (ws + (size_t)(1u << 20));        // 2 MB
  int2*  rev   = (int2*) (ws + (size_t)(3u << 20));        // 4 MB
  float* ybuf  = (float*)(ws + (size_t)(7u << 20));        // 16 MB
  float* hbuf  = (float*)(ws + (size_t)(23u << 20));       // 16 MB

  k_gemm<DD, true><<<M_TOT / 64, 512, 0, stream>>>(obs, W1, ybuf, maskf, degi, pxy);
  k_topk<<<dim3(BB, NN / 16), 256, 0, stream>>>(pxy, maskf, nbr, degi);
  k_graph<<<BB, 1024, 0, stream>>>(degi, maskf, nbr, cur, dinv, rev);
  k_gcnc<<<dim3(BB, HH / 8), 1024, 0, stream>>>(ybuf, dinv, degi, cur, rev, b1, hbuf);
  k_gemm<HH, false><<<M_TOT / 64, 512, 0, stream>>>(hbuf, W2, ybuf, nullptr, nullptr, nullptr);
  k_gcnc<<<dim3(BB, HH / 8), 1024, 0, stream>>>(ybuf, dinv, degi, cur, rev, b2, hbuf);
  k_out<<<M_TOT / 256, 256, 0, stream>>>(hbuf, Wo, bo, maskf, out);
}